// Round 5
// baseline (735.274 us; speedup 1.0000x reference)
//
#include <hip/hip_runtime.h>
#include <hip/hip_bf16.h>

typedef unsigned char u8;
typedef unsigned short u16;
typedef unsigned int u32;
typedef float f32x4 __attribute__((ext_vector_type(4)));
typedef short s16x8 __attribute__((ext_vector_type(8)));

#define MEM    2000
#define FEA    256
#define SLSTR  2056      // fp8 a row stride (bytes)
#define OSTR   265       // out-stage row stride (f32)
#define G1BASE 34816     // G1 ring slots 0..2 (slot 3 overlays sX at 0)
#define G2BASE 66560     // G2 ring 4x16384
#define POOLSZ 133120
#define OUTN   8388608   // 32*256*32*32

typedef const __attribute__((address_space(1))) u32* gp1;
typedef __attribute__((address_space(3))) u32* lp3;

__device__ __forceinline__ void gl_lds16(const void* g, void* l) {
    __builtin_amdgcn_global_load_lds((gp1)g, (lp3)l, 16, 0, 0);
}
__device__ __forceinline__ void pipe_bar() {
    __builtin_amdgcn_sched_barrier(0);
    __builtin_amdgcn_s_barrier();
    __builtin_amdgcn_sched_barrier(0);
}
__device__ __forceinline__ void lds_bar() {
    asm volatile("s_waitcnt lgkmcnt(0)" ::: "memory");
    pipe_bar();
}

__device__ __forceinline__ u16 f2b(float f) {
    u32 u = __builtin_bit_cast(u32, f);
    u = u + 0x7fffu + ((u >> 16) & 1u);
    return (u16)(u >> 16);
}
__device__ __forceinline__ u32 cvtpk(float a, float b) {
    u32 r;
    asm("v_cvt_pk_bf16_f32 %0, %1, %2" : "=v"(r) : "v"(a), "v"(b));
    return r;   // low16 = bf16(a), high16 = bf16(b)
}
__device__ __forceinline__ float unlo(u32 p) { return __builtin_bit_cast(float, p << 16); }
__device__ __forceinline__ float unhi(u32 p) { return __builtin_bit_cast(float, p & 0xffff0000u); }
// exact f32 -> e4m3fn (RNE) incl subnormals (prep only)
__device__ __forceinline__ u8 f2e4m3(float x) {
    float ax = fabsf(x);
    u32 s = (__builtin_bit_cast(u32, x) >> 24) & 0x80u;
    if (ax >= 448.f) return (u8)(s | 0x7e);
    if (ax < 0.015625f) {
        int q = (int)rintf(ax * 512.f);
        return (u8)(s | (u32)q);
    }
    int e = (int)(__builtin_bit_cast(u32, ax) >> 23) - 127;
    float scale = __builtin_bit_cast(float, (u32)((127 - e + 3) << 23));
    int q = (int)rintf(ax * scale);
    int E = e + 7;
    if (q == 16) { q = 8; E += 1; if (E > 15) return (u8)(s | 0x7e); }
    return (u8)(s | (u32)(E << 3) | (u32)(q & 7));
}
// fast f32 -> e4m3fn for v in {0} U [0.15, 64]
__device__ __forceinline__ u32 f2e4m3_fast(float v) {
    u32 u = __builtin_bit_cast(u32, v);
    u += 0x0007FFFFu + ((u >> 20) & 1u);
    int bb = (int)(u >> 20) - 0x3C0;
    return bb < 0 ? 0u : (u32)bb;
}

// ---------------- prep ----------------
__global__ __launch_bounds__(256) void prep_kernel(const float* __restrict__ W,
                                                   u16* __restrict__ Wbs,
                                                   u8* __restrict__ WTc,
                                                   float* __restrict__ sqv,
                                                   float* __restrict__ loss) {
    const int blk = blockIdx.x, t = threadIdx.x;
    const int m0 = blk * 8;
    {
        const int sl = t >> 5, cl = t & 31;
        const int slot = m0 + sl;
        const int ch0 = cl * 8;
        const float* wr = W + slot * 256 + ch0;
        f32x4 v0 = *(const f32x4*)wr;
        f32x4 v1 = *(const f32x4*)(wr + 4);
        float ss = v0[0]*v0[0] + v0[1]*v0[1] + v0[2]*v0[2] + v0[3]*v0[3]
                 + v1[0]*v1[0] + v1[1]*v1[1] + v1[2]*v1[2] + v1[3]*v1[3];
        ss += __shfl_xor(ss, 1); ss += __shfl_xor(ss, 2); ss += __shfl_xor(ss, 4);
        ss += __shfl_xor(ss, 8); ss += __shfl_xor(ss, 16);
        if (cl == 0) sqv[slot] = ss;
        s16x8 pk;
#pragma unroll
        for (int i = 0; i < 4; ++i) { pk[i] = (short)f2b(v0[i]); pk[4 + i] = (short)f2b(v1[i]); }
        *(s16x8*)&Wbs[slot * 256 + (ch0 ^ ((slot & 7) << 3))] = pk;
    }
    {
        const int ch = t;
        const int chunk = m0 >> 6, kl0 = m0 & 63;
        u32 lo = 0, hi = 0;
#pragma unroll
        for (int i = 0; i < 8; ++i) {
            u32 bb = f2e4m3(W[(m0 + i) * 256 + ch] * 16.f);
            if (i < 4) lo |= bb << (i * 8); else hi |= bb << ((i - 4) * 8);
        }
        u8* dst = WTc + chunk * 16384 + ch * 64 + (kl0 ^ ((ch & 7) << 3));
        *(u32*)dst = lo;
        *(u32*)(dst + 4) = hi;
    }
    if (blk == 0 && t == 0) {
        loss[0] = 0.0f;
        loss[1] = -2000.0f / (2000.0f * 1999.0f);
    }
}

// ---------------- main fused kernel: 64 rows/block, 512 blocks ----------------
__global__ __launch_bounds__(512, 2) void main_kernel(
        const float* __restrict__ inp, const float* __restrict__ posb,
        const u16* __restrict__ Wbs, const u8* __restrict__ WTc,
        const float* __restrict__ sqv, float* __restrict__ out,
        float* __restrict__ loss) {
    __shared__ __align__(16) u8 pool[POOLSZ];
    __shared__ float sPM[4][64];
    __shared__ float sPZ[4][64];
    __shared__ int   sPI[4][64];
    __shared__ float sPD[4][64];
    __shared__ float sSS[8][64];
    __shared__ float sMax[64];
    __shared__ float sThr[64];
    __shared__ float sInv[64];

    const int t = threadIdx.x;
    const int w = t >> 6, lane = t & 63;
    const int ar = lane & 15, ag = lane >> 4;
    const int blk = blockIdx.x, b = blk >> 4, hw0 = (blk & 15) << 6;
    const int rot = (blk >> 3) & 31;
    const int q = w & 3, rh = w >> 2;
    const u8* WbsB = (const u8*)Wbs;

    // ---- G1 prologue: chunks 0..2 -> slots 0..2 ----
#pragma unroll
    for (int c = 0; c < 3; ++c) {
        const int cc = (c + rot) & 31;
        const u8* src = WbsB + cc * 32768 + w * 4096 + lane * 16;
        u8* dst = pool + G1BASE + c * 32768 + w * 4096;
#pragma unroll
        for (int i = 0; i < 4; ++i) gl_lds16(src + i * 1024, dst + i * 1024);
    }

    // ---- stage xr (64 rows) as bf16 pairs + sum(x^2); PLAIN 264-u16 stride (no XOR) ----
    {
        const float* ip = inp + (size_t)b * 262144 + hw0 + lane;
        const float* pp = posb + hw0 + lane;
        u16* sX = (u16*)pool;
        float ss = 0.f;
#pragma unroll
        for (int j = 0; j < 16; ++j) {
            const int ch = w * 32 + 2 * j;
            float v0 = ip[ch * 1024] + pp[ch * 1024];
            float v1 = ip[(ch + 1) * 1024] + pp[(ch + 1) * 1024];
            ss += v0 * v0 + v1 * v1;
            u32 pkx = (u32)f2b(v0) | ((u32)f2b(v1) << 16);
            *(u32*)(sX + lane * 264 + ch) = pkx;
        }
        sSS[w][lane] = ss;
    }
    lds_bar();

    // ---- xr B-fragments for this wave's 32 rows (2 row-tiles) ----
    s16x8 af[2][8];
    {
        const u16* sX = (const u16*)pool;
#pragma unroll
        for (int rl = 0; rl < 2; ++rl)
#pragma unroll
            for (int kk = 0; kk < 8; ++kk) {
                const int row = rh * 32 + rl * 16 + ar;
                af[rl][kk] = *(const s16x8*)(sX + row * 264 + kk * 32 + ag * 8);
            }
    }
    asm volatile("s_waitcnt lgkmcnt(0)" ::: "memory");
    __builtin_amdgcn_sched_barrier(0);

    // ---- GEMM1: stream Wbs; logits -> packed bf16 regs; online max/argmax/Z ----
    u32 pk[32][2][2];
    float bm[2] = {-3e38f, -3e38f};
    int   bi[2] = {0x7fffffff, 0x7fffffff};
    float zz[2] = {0.f, 0.f};
    {
        const int rowoff = (q * 16 + ar) * 512;
        const int swz = (ar & 7) << 4;
        const int c31 = (31 - rot) & 31;
#pragma unroll
        for (int c = 0; c < 32; ++c) {
            if (c <= 29)      asm volatile("s_waitcnt vmcnt(8)" ::: "memory");
            else if (c == 30) asm volatile("s_waitcnt vmcnt(4)" ::: "memory");
            else              asm volatile("s_waitcnt vmcnt(0)" ::: "memory");
            pipe_bar();
            if (c <= 28) {
                const int cn = (c + 3 + rot) & 31;
                const int sl = (c + 3) & 3;
                const u8* src = WbsB + cn * 32768 + w * 4096 + lane * 16;
                u8* dst = (sl == 3 ? pool : pool + G1BASE + sl * 32768) + w * 4096;
#pragma unroll
                for (int i = 0; i < 4; ++i) gl_lds16(src + i * 1024, dst + i * 1024);
            }
            const int cs = c & 3;
            const u8* base = (cs == 3 ? pool : pool + G1BASE + cs * 32768);
            f32x4 a0 = {0.f, 0.f, 0.f, 0.f}, a1 = {0.f, 0.f, 0.f, 0.f};
#pragma unroll
            for (int kk = 0; kk < 8; ++kk) {
                s16x8 wf = *(const s16x8*)(base + ((rowoff + kk * 64 + ag * 16) ^ swz));
                a0 = __builtin_amdgcn_mfma_f32_16x16x32_bf16(wf, af[0][kk], a0, 0, 0, 0);
                a1 = __builtin_amdgcn_mfma_f32_16x16x32_bf16(wf, af[1][kk], a1, 0, 0, 0);
            }
            if (c == c31 && q != 0) {
#pragma unroll
                for (int e = 0; e < 4; ++e) { a0[e] = -3e38f; a1[e] = -3e38f; }
            }
            const int sb = (((c + rot) & 31) << 6) + q * 16 + ag * 4;
#pragma unroll
            for (int rl = 0; rl < 2; ++rl) {
                f32x4 a = rl ? a1 : a0;
                float ob = bm[rl];
#pragma unroll
                for (int e = 0; e < 4; ++e) {
                    float v = a[e]; int id = sb + e;
                    bool g = (v > bm[rl]) || (v == bm[rl] && id < bi[rl]);
                    bm[rl] = g ? v : bm[rl];
                    bi[rl] = g ? id : bi[rl];
                }
                zz[rl] *= __expf(ob - bm[rl]);   // ==1 when max unchanged
                zz[rl] += __expf(a[0] - bm[rl]) + __expf(a[1] - bm[rl])
                        + __expf(a[2] - bm[rl]) + __expf(a[3] - bm[rl]);
                pk[c][rl][0] = cvtpk(a[0], a[1]);
                pk[c][rl][1] = cvtpk(a[2], a[3]);
            }
        }
    }

    // ---- combine (m,i,z) across ag lanes ----
#pragma unroll
    for (int rl = 0; rl < 2; ++rl) {
#pragma unroll
        for (int d = 16; d < 64; d <<= 1) {
            float om = __shfl_xor(bm[rl], d);
            int   oi = __shfl_xor(bi[rl], d);
            float oz = __shfl_xor(zz[rl], d);
            bool g = (om > bm[rl]) || (om == bm[rl] && oi < bi[rl]);
            float nm = g ? om : bm[rl];
            zz[rl] = zz[rl] * __expf(bm[rl] - nm) + oz * __expf(om - nm);
            bm[rl] = nm;
            bi[rl] = g ? oi : bi[rl];
        }
    }
    if (lane < 16) {
#pragma unroll
        for (int rl = 0; rl < 2; ++rl) {
            const int row = rh * 32 + rl * 16 + ar;
            sPM[q][row] = bm[rl];
            sPZ[q][row] = zz[rl];
            sPI[q][row] = bi[rl];
        }
    }

    // ---- G2 prologue (ring region: old G1 slots, now dead) ----
#pragma unroll
    for (int c = 0; c < 3; ++c) {
        const int cc = (c + rot) & 31;
        const u8* src = WTc + cc * 16384 + w * 2048 + lane * 16;
        u8* dst = pool + G2BASE + c * 16384 + w * 2048;
#pragma unroll
        for (int i = 0; i < 2; ++i) gl_lds16(src + i * 1024, dst + i * 1024);
    }
    lds_bar();

    // ---- combiner 1: row max/argmax/Z -> sMax/sThr; compact loss ----
    if (t < 64) {
        float M = sPM[0][t]; int I = sPI[0][t];
#pragma unroll
        for (int qq = 1; qq < 4; ++qq) {
            float m2 = sPM[qq][t]; int i2 = sPI[qq][t];
            bool g = (m2 > M) || (m2 == M && i2 < I);
            M = g ? m2 : M; I = g ? i2 : I;
        }
        float Z = 0.f;
#pragma unroll
        for (int qq = 0; qq < 4; ++qq) Z += sPZ[qq][t] * __expf(sPM[qq][t] - M);
        sMax[t] = M;
        sThr[t] = 0.0025f * Z;
        float ssq = 0.f;
#pragma unroll
        for (int ww = 0; ww < 8; ++ww) ssq += sSS[ww][t];
        float term = ssq - 2.f * M + sqv[I];
#pragma unroll
        for (int d = 1; d < 64; d <<= 1) term += __shfl_xor(term, d);
        if (t == 0) atomicAdd(loss, term * (1.0f / 8388608.0f));
    }
    lds_bar();

    // ---- exp-pass: a = exp(l-M); mask; den; fp8 pack; rh0 -> LDS, rh1 -> regs ----
    u32 d8[32][2];
    float den[2] = {0.f, 0.f};
    float Mr[2], Tr[2];
#pragma unroll
    for (int rl = 0; rl < 2; ++rl) {
        const int row = rh * 32 + rl * 16 + ar;
        Mr[rl] = sMax[row];
        Tr[rl] = sThr[row];
    }
#pragma unroll
    for (int c = 0; c < 32; ++c) {
        const int sb = (((c + rot) & 31) << 6) + q * 16 + ag * 4;
#pragma unroll
        for (int rl = 0; rl < 2; ++rl) {
            const u32 p0 = pk[c][rl][0], p1 = pk[c][rl][1];
            float a0 = __expf(unlo(p0) - Mr[rl]);
            float a1 = __expf(unhi(p0) - Mr[rl]);
            float a2 = __expf(unlo(p1) - Mr[rl]);
            float a3 = __expf(unhi(p1) - Mr[rl]);
            bool k0 = a0 > Tr[rl], k1 = a1 > Tr[rl], k2 = a2 > Tr[rl], k3 = a3 > Tr[rl];
            den[rl] += (k0 ? a0 : 0.f) + (k1 ? a1 : 0.f) + (k2 ? a2 : 0.f) + (k3 ? a3 : 0.f);
            u32 w32 = (k0 ? f2e4m3_fast(a0 * 64.f) : 0u)
                    | ((k1 ? f2e4m3_fast(a1 * 64.f) : 0u) << 8)
                    | ((k2 ? f2e4m3_fast(a2 * 64.f) : 0u) << 16)
                    | ((k3 ? f2e4m3_fast(a3 * 64.f) : 0u) << 24);
            if (rh == 0) *(u32*)(pool + (rl * 16 + ar) * SLSTR + sb) = w32;
            else d8[c][rl] = w32;
        }
    }
#pragma unroll
    for (int rl = 0; rl < 2; ++rl) {
        den[rl] += __shfl_xor(den[rl], 16);
        den[rl] += __shfl_xor(den[rl], 32);
    }
    if (lane < 16) {
#pragma unroll
        for (int rl = 0; rl < 2; ++rl) sPD[q][rh * 32 + rl * 16 + ar] = den[rl];
    }
    lds_bar();
    if (t < 64) {
        float dd = sPD[0][t] + sPD[1][t] + sPD[2][t] + sPD[3][t];
        sInv[t] = dd > 0.f ? 1.0f / (1024.0f * dd) : 0.0f;
    }
    lds_bar();

    // ---- GEMM2: two 32-row halves over streamed WTc ----
    const int ch0 = w * 32 + ar;
    const int ch1 = ch0 + 16;
    int bo[2][2];
#pragma unroll
    for (int kk = 0; kk < 2; ++kk) {
        bo[0][kk] = (ch0 * 64 + kk * 32 + ag * 8) ^ ((ch0 & 7) << 3);
        bo[1][kk] = (ch1 * 64 + kk * 32 + ag * 8) ^ ((ch1 & 7) << 3);
    }
    const u8* sLr0 = pool + ar * SLSTR + ag * 8;
    const u8* sLr1 = pool + (16 + ar) * SLSTR + ag * 8;
    f32x4 oA[2], oB[2], oC[2], oD[2];

#pragma unroll
    for (int h = 0; h < 2; ++h) {
        f32x4 o00 = {0.f,0.f,0.f,0.f}, o01 = {0.f,0.f,0.f,0.f};
        f32x4 o10 = {0.f,0.f,0.f,0.f}, o11 = {0.f,0.f,0.f,0.f};
#pragma unroll
        for (int c = 0; c < 32; ++c) {
            if (c <= 29)      asm volatile("s_waitcnt vmcnt(4)" ::: "memory");
            else if (c == 30) asm volatile("s_waitcnt vmcnt(2)" ::: "memory");
            else              asm volatile("s_waitcnt vmcnt(0)" ::: "memory");
            pipe_bar();
            if (c <= 28) {
                const int cn = (c + 3 + rot) & 31;
                const u8* src = WTc + cn * 16384 + w * 2048 + lane * 16;
                u8* dst = pool + G2BASE + (((c + 3) & 3) << 14) + w * 2048;
#pragma unroll
                for (int i = 0; i < 2; ++i) gl_lds16(src + i * 1024, dst + i * 1024);
            }
            const u8* base = pool + G2BASE + ((c & 3) << 14);
            const int cc64 = ((c + rot) & 31) << 6;
            long long A00 = *(const long long*)(sLr0 + cc64);
            long long A01 = *(const long long*)(sLr0 + cc64 + 32);
            long long A10 = *(const long long*)(sLr1 + cc64);
            long long A11 = *(const long long*)(sLr1 + cc64 + 32);
            long long B00 = *(const long long*)(base + bo[0][0]);
            long long B01 = *(const long long*)(base + bo[0][1]);
            long long B10 = *(const long long*)(base + bo[1][0]);
            long long B11 = *(const long long*)(base + bo[1][1]);
            o00 = __builtin_amdgcn_mfma_f32_16x16x32_fp8_fp8(A00, B00, o00, 0, 0, 0);
            o00 = __builtin_amdgcn_mfma_f32_16x16x32_fp8_fp8(A01, B01, o00, 0, 0, 0);
            o01 = __builtin_amdgcn_mfma_f32_16x16x32_fp8_fp8(A10, B00, o01, 0, 0, 0);
            o01 = __builtin_amdgcn_mfma_f32_16x16x32_fp8_fp8(A11, B01, o01, 0, 0, 0);
            o10 = __builtin_amdgcn_mfma_f32_16x16x32_fp8_fp8(A00, B10, o10, 0, 0, 0);
            o10 = __builtin_amdgcn_mfma_f32_16x16x32_fp8_fp8(A01, B11, o10, 0, 0, 0);
            o11 = __builtin_amdgcn_mfma_f32_16x16x32_fp8_fp8(A10, B10, o11, 0, 0, 0);
            o11 = __builtin_amdgcn_mfma_f32_16x16x32_fp8_fp8(A11, B11, o11, 0, 0, 0);
        }
        oA[h] = o00; oB[h] = o01; oC[h] = o10; oD[h] = o11;
        lds_bar();
        if (h == 0) {
            // dump rh=1 fp8 a into a-region (local rows 0..31 = global 32..63)
            if (rh == 1) {
#pragma unroll
                for (int c = 0; c < 32; ++c) {
                    const int sb = (((c + rot) & 31) << 6) + q * 16 + ag * 4;
#pragma unroll
                    for (int rl = 0; rl < 2; ++rl)
                        *(u32*)(pool + (rl * 16 + ar) * SLSTR + sb) = d8[c][rl];
                }
            }
            // h1 prologue
#pragma unroll
            for (int c = 0; c < 3; ++c) {
                const int cc = (c + rot) & 31;
                const u8* src = WTc + cc * 16384 + w * 2048 + lane * 16;
                u8* dst = pool + G2BASE + c * 16384 + w * 2048;
#pragma unroll
                for (int i = 0; i < 2; ++i) gl_lds16(src + i * 1024, dst + i * 1024);
            }
            lds_bar();
        }
    }

    // ---- out-stage both halves + coalesced store ----
    {
        float* sO = (float*)pool;
#pragma unroll
        for (int h = 0; h < 2; ++h) {
#pragma unroll
            for (int i = 0; i < 4; ++i) {
                const int r0 = h * 32 + ag * 4 + i;
                const int r1 = r0 + 16;
                sO[r0 * OSTR + ch0] = oA[h][i] * sInv[r0];
                sO[r1 * OSTR + ch0] = oB[h][i] * sInv[r1];
                sO[r0 * OSTR + ch1] = oC[h][i] * sInv[r0];
                sO[r1 * OSTR + ch1] = oD[h][i] * sInv[r1];
            }
        }
    }
    lds_bar();
    {
        const float* sO = (const float*)pool;
        float* op = out + (size_t)b * 262144 + hw0 + lane;
#pragma unroll
        for (int i = 0; i < 32; ++i) {
            const int ch = w * 32 + i;
            op[ch * 1024] = sO[lane * OSTR + ch];
        }
    }
}

// ---------------- distance loss (unchanged) ----------------
__global__ __launch_bounds__(256) void dist_kernel(const u16* __restrict__ Wbs,
                                                   const float* __restrict__ sqv,
                                                   float* __restrict__ dl) {
    __shared__ float red[4];
    int t = threadIdx.x, w = t >> 6, lane = t & 63;
    int ar = lane & 15, ag = lane >> 4;
    int i0 = blockIdx.x << 4;
    int si = i0 + ar;
    s16x8 af[8];
#pragma unroll
    for (int q = 0; q < 8; ++q)
        af[q] = *(const s16x8*)&Wbs[si * 256 + ((q * 32 + ag * 8) ^ ((si & 7) << 3))];
    float sqi[4];
#pragma unroll
    for (int e = 0; e < 4; ++e) sqi[e] = sqv[i0 + (ag << 2) + e];
    float sum = 0.f;
    for (int jt = w; jt < 125; jt += 4) {
        int j0 = jt << 4, sj0 = j0 + ar;
        f32x4 acc = {0.f, 0.f, 0.f, 0.f};
#pragma unroll
        for (int q = 0; q < 8; ++q) {
            s16x8 bf = *(const s16x8*)&Wbs[sj0 * 256 + ((q * 32 + ag * 8) ^ ((sj0 & 7) << 3))];
            acc = __builtin_amdgcn_mfma_f32_16x16x32_bf16(af[q], bf, acc, 0, 0, 0);
        }
        float sqj = sqv[sj0];
#pragma unroll
        for (int e = 0; e < 4; ++e) {
            float dist = 1.0f - (sqi[e] + sqj - 2.0f * acc[e]);
            sum += dist > 0.f ? dist : 0.f;
        }
    }
#pragma unroll
    for (int d = 1; d < 64; d <<= 1) sum += __shfl_xor(sum, d);
    if (lane == 0) red[w] = sum;
    __syncthreads();
    if (t == 0) {
        float s = red[0] + red[1] + red[2] + red[3];
        atomicAdd(dl, s * (1.0f / (2000.0f * 1999.0f)));
    }
}

extern "C" void kernel_launch(void* const* d_in, const int* in_sizes, int n_in,
                              void* d_out, int out_size, void* d_ws, size_t ws_size,
                              hipStream_t stream) {
    (void)in_sizes; (void)n_in; (void)out_size; (void)ws_size;
    const float* inp  = (const float*)d_in[0];
    const float* W    = (const float*)d_in[2];
    const float* posb = (const float*)d_in[3];
    float* out = (float*)d_out;

    u16* Wbs = (u16*)d_ws;                                   // 2048*256*2 = 1,048,576 B
    u8*  WTc = (u8*)d_ws + 1048576;                          // 32*16384   =   524,288 B
    float* sqv = (float*)((u8*)d_ws + 1048576 + 524288);     // 2000*4     =     8,000 B

    hipLaunchKernelGGL(prep_kernel, dim3(250), dim3(256), 0, stream, W, Wbs, WTc, sqv, out + OUTN);
    hipLaunchKernelGGL(main_kernel, dim3(512), dim3(512), 0, stream, inp, posb, Wbs, WTc, sqv, out, out + OUTN);
    hipLaunchKernelGGL(dist_kernel, dim3(125), dim3(256), 0, stream, Wbs, sqv, out + OUTN + 1);
}

// Round 6
// 733.887 us; speedup vs baseline: 1.0019x; 1.0019x over previous
//
#include <hip/hip_runtime.h>
#include <hip/hip_bf16.h>

typedef unsigned char u8;
typedef unsigned short u16;
typedef unsigned int u32;
typedef float f32x4 __attribute__((ext_vector_type(4)));
typedef short s16x8 __attribute__((ext_vector_type(8)));

#define MEM    2000
#define FEA    256
#define SLSTR  2056      // fp8 a row stride (bytes)
#define OSTR   265       // out-stage row stride (f32)
#define G1BASE 34816     // G1 ring slots 0..2 (slot 3 overlays sX at 0)
#define G2BASE 66560     // G2 ring 4x16384
#define POOLSZ 133120
#define OUTN   8388608   // 32*256*32*32

typedef const __attribute__((address_space(1))) u32* gp1;
typedef __attribute__((address_space(3))) u32* lp3;

__device__ __forceinline__ void gl_lds16(const void* g, void* l) {
    __builtin_amdgcn_global_load_lds((gp1)g, (lp3)l, 16, 0, 0);
}
__device__ __forceinline__ void pipe_bar() {
    __builtin_amdgcn_sched_barrier(0);
    __builtin_amdgcn_s_barrier();
    __builtin_amdgcn_sched_barrier(0);
}
__device__ __forceinline__ void lds_bar() {
    asm volatile("s_waitcnt lgkmcnt(0)" ::: "memory");
    pipe_bar();
}

__device__ __forceinline__ u16 f2b(float f) {
    u32 u = __builtin_bit_cast(u32, f);
    u = u + 0x7fffu + ((u >> 16) & 1u);
    return (u16)(u >> 16);
}
__device__ __forceinline__ u32 cvtpk(float a, float b) {
    u32 r;
    asm("v_cvt_pk_bf16_f32 %0, %1, %2" : "=v"(r) : "v"(a), "v"(b));
    return r;   // low16 = bf16(a), high16 = bf16(b)
}
__device__ __forceinline__ float unlo(u32 p) { return __builtin_bit_cast(float, p << 16); }
__device__ __forceinline__ float unhi(u32 p) { return __builtin_bit_cast(float, p & 0xffff0000u); }
// exact f32 -> e4m3fn (RNE) incl subnormals (prep only)
__device__ __forceinline__ u8 f2e4m3(float x) {
    float ax = fabsf(x);
    u32 s = (__builtin_bit_cast(u32, x) >> 24) & 0x80u;
    if (ax >= 448.f) return (u8)(s | 0x7e);
    if (ax < 0.015625f) {
        int q = (int)rintf(ax * 512.f);
        return (u8)(s | (u32)q);
    }
    int e = (int)(__builtin_bit_cast(u32, ax) >> 23) - 127;
    float scale = __builtin_bit_cast(float, (u32)((127 - e + 3) << 23));
    int q = (int)rintf(ax * scale);
    int E = e + 7;
    if (q == 16) { q = 8; E += 1; if (E > 15) return (u8)(s | 0x7e); }
    return (u8)(s | (u32)(E << 3) | (u32)(q & 7));
}
// fast f32 -> e4m3fn for v in {0} U [0.15, 64]
__device__ __forceinline__ u32 f2e4m3_fast(float v) {
    u32 u = __builtin_bit_cast(u32, v);
    u += 0x0007FFFFu + ((u >> 20) & 1u);
    int bb = (int)(u >> 20) - 0x3C0;
    return bb < 0 ? 0u : (u32)bb;
}

// ---------------- prep ----------------
__global__ __launch_bounds__(256) void prep_kernel(const float* __restrict__ W,
                                                   u16* __restrict__ Wbs,
                                                   u8* __restrict__ WTc,
                                                   float* __restrict__ sqv,
                                                   float* __restrict__ loss) {
    const int blk = blockIdx.x, t = threadIdx.x;
    const int m0 = blk * 8;
    {
        const int sl = t >> 5, cl = t & 31;
        const int slot = m0 + sl;
        const int ch0 = cl * 8;
        const float* wr = W + slot * 256 + ch0;
        f32x4 v0 = *(const f32x4*)wr;
        f32x4 v1 = *(const f32x4*)(wr + 4);
        float ss = v0[0]*v0[0] + v0[1]*v0[1] + v0[2]*v0[2] + v0[3]*v0[3]
                 + v1[0]*v1[0] + v1[1]*v1[1] + v1[2]*v1[2] + v1[3]*v1[3];
        ss += __shfl_xor(ss, 1); ss += __shfl_xor(ss, 2); ss += __shfl_xor(ss, 4);
        ss += __shfl_xor(ss, 8); ss += __shfl_xor(ss, 16);
        if (cl == 0) sqv[slot] = ss;
        s16x8 pk;
#pragma unroll
        for (int i = 0; i < 4; ++i) { pk[i] = (short)f2b(v0[i]); pk[4 + i] = (short)f2b(v1[i]); }
        *(s16x8*)&Wbs[slot * 256 + (ch0 ^ ((slot & 7) << 3))] = pk;
    }
    {
        const int ch = t;
        const int chunk = m0 >> 6, kl0 = m0 & 63;
        u32 lo = 0, hi = 0;
#pragma unroll
        for (int i = 0; i < 8; ++i) {
            u32 bb = f2e4m3(W[(m0 + i) * 256 + ch] * 16.f);
            if (i < 4) lo |= bb << (i * 8); else hi |= bb << ((i - 4) * 8);
        }
        u8* dst = WTc + chunk * 16384 + ch * 64 + (kl0 ^ ((ch & 7) << 3));
        *(u32*)dst = lo;
        *(u32*)(dst + 4) = hi;
    }
    if (blk == 0 && t == 0) {
        loss[0] = 0.0f;
        loss[1] = -2000.0f / (2000.0f * 1999.0f);
    }
}

// ---------------- main fused kernel: 64 rows/block, 512 blocks, 1 block/CU ----------------
__global__ __launch_bounds__(512, 1) void main_kernel(
        const float* __restrict__ inp, const float* __restrict__ posb,
        const u16* __restrict__ Wbs, const u8* __restrict__ WTc,
        const float* __restrict__ sqv, float* __restrict__ out,
        float* __restrict__ loss) {
    __shared__ __align__(16) u8 pool[POOLSZ];
    __shared__ float sPM[4][64];
    __shared__ float sPZ[4][64];
    __shared__ int   sPI[4][64];
    __shared__ float sPD[4][64];
    __shared__ float sSS[8][64];
    __shared__ float sMax[64];
    __shared__ float sThr[64];
    __shared__ float sInv[64];

    const int t = threadIdx.x;
    const int w = t >> 6, lane = t & 63;
    const int ar = lane & 15, ag = lane >> 4;
    const int blk = blockIdx.x, b = blk >> 4, hw0 = (blk & 15) << 6;
    const int rot = (blk >> 3) & 31;
    const int q = w & 3, rh = w >> 2;
    const u8* WbsB = (const u8*)Wbs;

    // ---- G1 prologue: chunks 0..2 -> slots 0..2 ----
#pragma unroll
    for (int c = 0; c < 3; ++c) {
        const int cc = (c + rot) & 31;
        const u8* src = WbsB + cc * 32768 + w * 4096 + lane * 16;
        u8* dst = pool + G1BASE + c * 32768 + w * 4096;
#pragma unroll
        for (int i = 0; i < 4; ++i) gl_lds16(src + i * 1024, dst + i * 1024);
    }

    // ---- stage xr (64 rows) as bf16 pairs + sum(x^2); plain 264-u16 stride ----
    {
        const float* ip = inp + (size_t)b * 262144 + hw0 + lane;
        const float* pp = posb + hw0 + lane;
        u16* sX = (u16*)pool;
        float ss = 0.f;
#pragma unroll
        for (int j = 0; j < 16; ++j) {
            const int ch = w * 32 + 2 * j;
            float v0 = ip[ch * 1024] + pp[ch * 1024];
            float v1 = ip[(ch + 1) * 1024] + pp[(ch + 1) * 1024];
            ss += v0 * v0 + v1 * v1;
            u32 pkx = (u32)f2b(v0) | ((u32)f2b(v1) << 16);
            *(u32*)(sX + lane * 264 + ch) = pkx;
        }
        sSS[w][lane] = ss;
    }
    lds_bar();

    // ---- xr B-fragments for this wave's 32 rows (2 row-tiles) ----
    s16x8 af[2][8];
    {
        const u16* sX = (const u16*)pool;
#pragma unroll
        for (int rl = 0; rl < 2; ++rl)
#pragma unroll
            for (int kk = 0; kk < 8; ++kk) {
                const int row = rh * 32 + rl * 16 + ar;
                af[rl][kk] = *(const s16x8*)(sX + row * 264 + kk * 32 + ag * 8);
            }
    }
    asm volatile("s_waitcnt lgkmcnt(0)" ::: "memory");
    __builtin_amdgcn_sched_barrier(0);

    // ---- GEMM1: stream Wbs; logits -> packed bf16 regs; online max/argmax/Z ----
    u32 pk[32][2][2];
    float bm[2] = {-3e38f, -3e38f};
    int   bi[2] = {0x7fffffff, 0x7fffffff};
    float zz[2] = {0.f, 0.f};
    {
        const int rowoff = (q * 16 + ar) * 512;
        const int swz = (ar & 7) << 4;
        const int c31 = (31 - rot) & 31;
#pragma unroll
        for (int c = 0; c < 32; ++c) {
            if (c <= 29)      asm volatile("s_waitcnt vmcnt(8)" ::: "memory");
            else if (c == 30) asm volatile("s_waitcnt vmcnt(4)" ::: "memory");
            else              asm volatile("s_waitcnt vmcnt(0)" ::: "memory");
            pipe_bar();
            if (c <= 28) {
                const int cn = (c + 3 + rot) & 31;
                const int sl = (c + 3) & 3;
                const u8* src = WbsB + cn * 32768 + w * 4096 + lane * 16;
                u8* dst = (sl == 3 ? pool : pool + G1BASE + sl * 32768) + w * 4096;
#pragma unroll
                for (int i = 0; i < 4; ++i) gl_lds16(src + i * 1024, dst + i * 1024);
            }
            const int cs = c & 3;
            const u8* base = (cs == 3 ? pool : pool + G1BASE + cs * 32768);
            f32x4 a0 = {0.f, 0.f, 0.f, 0.f}, a1 = {0.f, 0.f, 0.f, 0.f};
#pragma unroll
            for (int kk = 0; kk < 8; ++kk) {
                s16x8 wf = *(const s16x8*)(base + ((rowoff + kk * 64 + ag * 16) ^ swz));
                a0 = __builtin_amdgcn_mfma_f32_16x16x32_bf16(wf, af[0][kk], a0, 0, 0, 0);
                a1 = __builtin_amdgcn_mfma_f32_16x16x32_bf16(wf, af[1][kk], a1, 0, 0, 0);
            }
            if (c == c31 && q != 0) {
#pragma unroll
                for (int e = 0; e < 4; ++e) { a0[e] = -3e38f; a1[e] = -3e38f; }
            }
            const int sb = (((c + rot) & 31) << 6) + q * 16 + ag * 4;
#pragma unroll
            for (int rl = 0; rl < 2; ++rl) {
                f32x4 a = rl ? a1 : a0;
                float ob = bm[rl];
#pragma unroll
                for (int e = 0; e < 4; ++e) {
                    float v = a[e]; int id = sb + e;
                    bool g = (v > bm[rl]) || (v == bm[rl] && id < bi[rl]);
                    bm[rl] = g ? v : bm[rl];
                    bi[rl] = g ? id : bi[rl];
                }
                zz[rl] *= __expf(ob - bm[rl]);   // ==1 when max unchanged
                zz[rl] += __expf(a[0] - bm[rl]) + __expf(a[1] - bm[rl])
                        + __expf(a[2] - bm[rl]) + __expf(a[3] - bm[rl]);
                pk[c][rl][0] = cvtpk(a[0], a[1]);
                pk[c][rl][1] = cvtpk(a[2], a[3]);
            }
        }
    }

    // ---- combine (m,i,z) across ag lanes ----
#pragma unroll
    for (int rl = 0; rl < 2; ++rl) {
#pragma unroll
        for (int d = 16; d < 64; d <<= 1) {
            float om = __shfl_xor(bm[rl], d);
            int   oi = __shfl_xor(bi[rl], d);
            float oz = __shfl_xor(zz[rl], d);
            bool g = (om > bm[rl]) || (om == bm[rl] && oi < bi[rl]);
            float nm = g ? om : bm[rl];
            zz[rl] = zz[rl] * __expf(bm[rl] - nm) + oz * __expf(om - nm);
            bm[rl] = nm;
            bi[rl] = g ? oi : bi[rl];
        }
    }
    if (lane < 16) {
#pragma unroll
        for (int rl = 0; rl < 2; ++rl) {
            const int row = rh * 32 + rl * 16 + ar;
            sPM[q][row] = bm[rl];
            sPZ[q][row] = zz[rl];
            sPI[q][row] = bi[rl];
        }
    }

    // ---- G2 prologue (ring region: old G1 slots, now dead) ----
#pragma unroll
    for (int c = 0; c < 3; ++c) {
        const int cc = (c + rot) & 31;
        const u8* src = WTc + cc * 16384 + w * 2048 + lane * 16;
        u8* dst = pool + G2BASE + c * 16384 + w * 2048;
#pragma unroll
        for (int i = 0; i < 2; ++i) gl_lds16(src + i * 1024, dst + i * 1024);
    }
    lds_bar();

    // ---- combiner 1: row max/argmax/Z -> sMax/sThr; compact loss ----
    if (t < 64) {
        float M = sPM[0][t]; int I = sPI[0][t];
#pragma unroll
        for (int qq = 1; qq < 4; ++qq) {
            float m2 = sPM[qq][t]; int i2 = sPI[qq][t];
            bool g = (m2 > M) || (m2 == M && i2 < I);
            M = g ? m2 : M; I = g ? i2 : I;
        }
        float Z = 0.f;
#pragma unroll
        for (int qq = 0; qq < 4; ++qq) Z += sPZ[qq][t] * __expf(sPM[qq][t] - M);
        sMax[t] = M;
        sThr[t] = 0.0025f * Z;
        float ssq = 0.f;
#pragma unroll
        for (int ww = 0; ww < 8; ++ww) ssq += sSS[ww][t];
        float term = ssq - 2.f * M + sqv[I];
#pragma unroll
        for (int d = 1; d < 64; d <<= 1) term += __shfl_xor(term, d);
        if (t == 0) atomicAdd(loss, term * (1.0f / 8388608.0f));
    }
    lds_bar();

    // ---- exp-pass: a = exp(l-M); mask; den; fp8 pack; rh0 -> LDS, rh1 -> regs ----
    u32 d8[32][2];
    float den[2] = {0.f, 0.f};
    float Mr[2], Tr[2];
#pragma unroll
    for (int rl = 0; rl < 2; ++rl) {
        const int row = rh * 32 + rl * 16 + ar;
        Mr[rl] = sMax[row];
        Tr[rl] = sThr[row];
    }
#pragma unroll
    for (int c = 0; c < 32; ++c) {
        const int sb = (((c + rot) & 31) << 6) + q * 16 + ag * 4;
#pragma unroll
        for (int rl = 0; rl < 2; ++rl) {
            const u32 p0 = pk[c][rl][0], p1 = pk[c][rl][1];
            float a0 = __expf(unlo(p0) - Mr[rl]);
            float a1 = __expf(unhi(p0) - Mr[rl]);
            float a2 = __expf(unlo(p1) - Mr[rl]);
            float a3 = __expf(unhi(p1) - Mr[rl]);
            bool k0 = a0 > Tr[rl], k1 = a1 > Tr[rl], k2 = a2 > Tr[rl], k3 = a3 > Tr[rl];
            den[rl] += (k0 ? a0 : 0.f) + (k1 ? a1 : 0.f) + (k2 ? a2 : 0.f) + (k3 ? a3 : 0.f);
            u32 w32 = (k0 ? f2e4m3_fast(a0 * 64.f) : 0u)
                    | ((k1 ? f2e4m3_fast(a1 * 64.f) : 0u) << 8)
                    | ((k2 ? f2e4m3_fast(a2 * 64.f) : 0u) << 16)
                    | ((k3 ? f2e4m3_fast(a3 * 64.f) : 0u) << 24);
            if (rh == 0) *(u32*)(pool + (rl * 16 + ar) * SLSTR + sb) = w32;
            else d8[c][rl] = w32;
        }
    }
#pragma unroll
    for (int rl = 0; rl < 2; ++rl) {
        den[rl] += __shfl_xor(den[rl], 16);
        den[rl] += __shfl_xor(den[rl], 32);
    }
    if (lane < 16) {
#pragma unroll
        for (int rl = 0; rl < 2; ++rl) sPD[q][rh * 32 + rl * 16 + ar] = den[rl];
    }
    lds_bar();
    if (t < 64) {
        float dd = sPD[0][t] + sPD[1][t] + sPD[2][t] + sPD[3][t];
        sInv[t] = dd > 0.f ? 1.0f / (1024.0f * dd) : 0.0f;
    }
    lds_bar();

    // ---- GEMM2: two 32-row halves over streamed WTc ----
    const int ch0 = w * 32 + ar;
    const int ch1 = ch0 + 16;
    int bo[2][2];
#pragma unroll
    for (int kk = 0; kk < 2; ++kk) {
        bo[0][kk] = (ch0 * 64 + kk * 32 + ag * 8) ^ ((ch0 & 7) << 3);
        bo[1][kk] = (ch1 * 64 + kk * 32 + ag * 8) ^ ((ch1 & 7) << 3);
    }
    const u8* sLr0 = pool + ar * SLSTR + ag * 8;
    const u8* sLr1 = pool + (16 + ar) * SLSTR + ag * 8;
    f32x4 oA[2], oB[2], oC[2], oD[2];

#pragma unroll
    for (int h = 0; h < 2; ++h) {
        f32x4 o00 = {0.f,0.f,0.f,0.f}, o01 = {0.f,0.f,0.f,0.f};
        f32x4 o10 = {0.f,0.f,0.f,0.f}, o11 = {0.f,0.f,0.f,0.f};
#pragma unroll
        for (int c = 0; c < 32; ++c) {
            if (c <= 29)      asm volatile("s_waitcnt vmcnt(4)" ::: "memory");
            else if (c == 30) asm volatile("s_waitcnt vmcnt(2)" ::: "memory");
            else              asm volatile("s_waitcnt vmcnt(0)" ::: "memory");
            pipe_bar();
            if (c <= 28) {
                const int cn = (c + 3 + rot) & 31;
                const u8* src = WTc + cn * 16384 + w * 2048 + lane * 16;
                u8* dst = pool + G2BASE + (((c + 3) & 3) << 14) + w * 2048;
#pragma unroll
                for (int i = 0; i < 2; ++i) gl_lds16(src + i * 1024, dst + i * 1024);
            }
            const u8* base = pool + G2BASE + ((c & 3) << 14);
            const int cc64 = ((c + rot) & 31) << 6;
            long long A00 = *(const long long*)(sLr0 + cc64);
            long long A01 = *(const long long*)(sLr0 + cc64 + 32);
            long long A10 = *(const long long*)(sLr1 + cc64);
            long long A11 = *(const long long*)(sLr1 + cc64 + 32);
            long long B00 = *(const long long*)(base + bo[0][0]);
            long long B01 = *(const long long*)(base + bo[0][1]);
            long long B10 = *(const long long*)(base + bo[1][0]);
            long long B11 = *(const long long*)(base + bo[1][1]);
            o00 = __builtin_amdgcn_mfma_f32_16x16x32_fp8_fp8(A00, B00, o00, 0, 0, 0);
            o00 = __builtin_amdgcn_mfma_f32_16x16x32_fp8_fp8(A01, B01, o00, 0, 0, 0);
            o01 = __builtin_amdgcn_mfma_f32_16x16x32_fp8_fp8(A10, B00, o01, 0, 0, 0);
            o01 = __builtin_amdgcn_mfma_f32_16x16x32_fp8_fp8(A11, B01, o01, 0, 0, 0);
            o10 = __builtin_amdgcn_mfma_f32_16x16x32_fp8_fp8(A00, B10, o10, 0, 0, 0);
            o10 = __builtin_amdgcn_mfma_f32_16x16x32_fp8_fp8(A01, B11, o10, 0, 0, 0);
            o11 = __builtin_amdgcn_mfma_f32_16x16x32_fp8_fp8(A10, B10, o11, 0, 0, 0);
            o11 = __builtin_amdgcn_mfma_f32_16x16x32_fp8_fp8(A11, B11, o11, 0, 0, 0);
        }
        oA[h] = o00; oB[h] = o01; oC[h] = o10; oD[h] = o11;
        lds_bar();
        if (h == 0) {
            // dump rh=1 fp8 a into a-region (local rows 0..31 = global 32..63)
            if (rh == 1) {
#pragma unroll
                for (int c = 0; c < 32; ++c) {
                    const int sb = (((c + rot) & 31) << 6) + q * 16 + ag * 4;
#pragma unroll
                    for (int rl = 0; rl < 2; ++rl)
                        *(u32*)(pool + (rl * 16 + ar) * SLSTR + sb) = d8[c][rl];
                }
            }
            // h1 prologue
#pragma unroll
            for (int c = 0; c < 3; ++c) {
                const int cc = (c + rot) & 31;
                const u8* src = WTc + cc * 16384 + w * 2048 + lane * 16;
                u8* dst = pool + G2BASE + c * 16384 + w * 2048;
#pragma unroll
                for (int i = 0; i < 2; ++i) gl_lds16(src + i * 1024, dst + i * 1024);
            }
            lds_bar();
        }
    }

    // ---- out-stage both halves + coalesced store ----
    {
        float* sO = (float*)pool;
#pragma unroll
        for (int h = 0; h < 2; ++h) {
#pragma unroll
            for (int i = 0; i < 4; ++i) {
                const int r0 = h * 32 + ag * 4 + i;
                const int r1 = r0 + 16;
                sO[r0 * OSTR + ch0] = oA[h][i] * sInv[r0];
                sO[r1 * OSTR + ch0] = oB[h][i] * sInv[r1];
                sO[r0 * OSTR + ch1] = oC[h][i] * sInv[r0];
                sO[r1 * OSTR + ch1] = oD[h][i] * sInv[r1];
            }
        }
    }
    lds_bar();
    {
        const float* sO = (const float*)pool;
        float* op = out + (size_t)b * 262144 + hw0 + lane;
#pragma unroll
        for (int i = 0; i < 32; ++i) {
            const int ch = w * 32 + i;
            op[ch * 1024] = sO[lane * OSTR + ch];
        }
    }
}

// ---------------- distance loss (unchanged) ----------------
__global__ __launch_bounds__(256) void dist_kernel(const u16* __restrict__ Wbs,
                                                   const float* __restrict__ sqv,
                                                   float* __restrict__ dl) {
    __shared__ float red[4];
    int t = threadIdx.x, w = t >> 6, lane = t & 63;
    int ar = lane & 15, ag = lane >> 4;
    int i0 = blockIdx.x << 4;
    int si = i0 + ar;
    s16x8 af[8];
#pragma unroll
    for (int q = 0; q < 8; ++q)
        af[q] = *(const s16x8*)&Wbs[si * 256 + ((q * 32 + ag * 8) ^ ((si & 7) << 3))];
    float sqi[4];
#pragma unroll
    for (int e = 0; e < 4; ++e) sqi[e] = sqv[i0 + (ag << 2) + e];
    float sum = 0.f;
    for (int jt = w; jt < 125; jt += 4) {
        int j0 = jt << 4, sj0 = j0 + ar;
        f32x4 acc = {0.f, 0.f, 0.f, 0.f};
#pragma unroll
        for (int q = 0; q < 8; ++q) {
            s16x8 bf = *(const s16x8*)&Wbs[sj0 * 256 + ((q * 32 + ag * 8) ^ ((sj0 & 7) << 3))];
            acc = __builtin_amdgcn_mfma_f32_16x16x32_bf16(af[q], bf, acc, 0, 0, 0);
        }
        float sqj = sqv[sj0];
#pragma unroll
        for (int e = 0; e < 4; ++e) {
            float dist = 1.0f - (sqi[e] + sqj - 2.0f * acc[e]);
            sum += dist > 0.f ? dist : 0.f;
        }
    }
#pragma unroll
    for (int d = 1; d < 64; d <<= 1) sum += __shfl_xor(sum, d);
    if (lane == 0) red[w] = sum;
    __syncthreads();
    if (t == 0) {
        float s = red[0] + red[1] + red[2] + red[3];
        atomicAdd(dl, s * (1.0f / (2000.0f * 1999.0f)));
    }
}

extern "C" void kernel_launch(void* const* d_in, const int* in_sizes, int n_in,
                              void* d_out, int out_size, void* d_ws, size_t ws_size,
                              hipStream_t stream) {
    (void)in_sizes; (void)n_in; (void)out_size; (void)ws_size;
    const float* inp  = (const float*)d_in[0];
    const float* W    = (const float*)d_in[2];
    const float* posb = (const float*)d_in[3];
    float* out = (float*)d_out;

    u16* Wbs = (u16*)d_ws;                                   // 2048*256*2 = 1,048,576 B
    u8*  WTc = (u8*)d_ws + 1048576;                          // 32*16384   =   524,288 B
    float* sqv = (float*)((u8*)d_ws + 1048576 + 524288);     // 2000*4     =     8,000 B

    hipLaunchKernelGGL(prep_kernel, dim3(250), dim3(256), 0, stream, W, Wbs, WTc, sqv, out + OUTN);
    hipLaunchKernelGGL(main_kernel, dim3(512), dim3(512), 0, stream, inp, posb, Wbs, WTc, sqv, out, out + OUTN);
    hipLaunchKernelGGL(dist_kernel, dim3(125), dim3(256), 0, stream, Wbs, sqv, out + OUTN + 1);
}